// Round 1
// baseline (1031.289 us; speedup 1.0000x reference)
//
#include <hip/hip_runtime.h>
#include <cstddef>

// Problem constants
#define BATCH 8
#define NQ    2048
#define NKV   2048
#define DIN   1024
#define HD    256

// Tiling
#define BM 64
#define BN 64
#define BK 16
#define PAD 4
#define LDA (BM + PAD)   // 68 floats: 2-way-at-most bank aliasing (free), 16B-aligned rows
#define LDB (BN + PAD)

__device__ __forceinline__ float sigmoidf_(float x) {
    return 1.0f / (1.0f + expf(-x));
}

// Generic GEMM: out = epilogue(X[M,K] @ W[K,N] + bv[N])
// MODE 0: sigmoid epilogue (Q projection)
// MODE 1: plain + bias (final projection)
template <int MODE>
__global__ __launch_bounds__(256)
void gemm_bias_kernel(const float* __restrict__ X, const float* __restrict__ W,
                      const float* __restrict__ bv, float* __restrict__ out,
                      int M, int N, int K)
{
    __shared__ float As[BK][LDA];
    __shared__ float Ws[BK][LDB];
    const int tid = threadIdx.x;
    const int tx = tid & 15, ty = tid >> 4;
    const int row0 = blockIdx.y * BM;
    const int col0 = blockIdx.x * BN;
    const int la_row = tid >> 2, la_col = (tid & 3) * 4;
    const int lw_row = tid >> 4, lw_col = (tid & 15) * 4;

    float acc[4][4] = {};

    const float* Xp = X + (size_t)(row0 + la_row) * K + la_col;
    const float* Wp = W + (size_t)lw_row * N + col0 + lw_col;

    for (int k0 = 0; k0 < K; k0 += BK) {
        float4 av = *(const float4*)(Xp + k0);
        float4 wv = *(const float4*)(Wp + (size_t)k0 * N);
        As[la_col + 0][la_row] = av.x;
        As[la_col + 1][la_row] = av.y;
        As[la_col + 2][la_row] = av.z;
        As[la_col + 3][la_row] = av.w;
        *(float4*)&Ws[lw_row][lw_col] = wv;
        __syncthreads();
#pragma unroll
        for (int kk = 0; kk < BK; ++kk) {
            float4 a4 = *(const float4*)&As[kk][ty * 4];
            float4 w4 = *(const float4*)&Ws[kk][tx * 4];
            float aa[4] = {a4.x, a4.y, a4.z, a4.w};
            float ww[4] = {w4.x, w4.y, w4.z, w4.w};
#pragma unroll
            for (int i = 0; i < 4; ++i)
#pragma unroll
                for (int j = 0; j < 4; ++j)
                    acc[i][j] = fmaf(aa[i], ww[j], acc[i][j]);
        }
        __syncthreads();
    }

    float bb[4];
#pragma unroll
    for (int j = 0; j < 4; ++j) bb[j] = bv[col0 + tx * 4 + j];
#pragma unroll
    for (int i = 0; i < 4; ++i) {
        int r = row0 + ty * 4 + i;
        float4 o;
        if (MODE == 0) {
            o.x = sigmoidf_(acc[i][0] + bb[0]);
            o.y = sigmoidf_(acc[i][1] + bb[1]);
            o.z = sigmoidf_(acc[i][2] + bb[2]);
            o.w = sigmoidf_(acc[i][3] + bb[3]);
        } else {
            o.x = acc[i][0] + bb[0];
            o.y = acc[i][1] + bb[1];
            o.z = acc[i][2] + bb[2];
            o.w = acc[i][3] + bb[3];
        }
        *(float4*)&out[(size_t)r * N + col0 + tx * 4] = o;
    }
}

// Fused K and V projection: expK = exp(x@wk + bk); expKV = expK * (x@wv + bv)
__global__ __launch_bounds__(256)
void proj_kv_kernel(const float* __restrict__ X,
                    const float* __restrict__ Wk, const float* __restrict__ bk,
                    const float* __restrict__ Wv, const float* __restrict__ bvv,
                    float* __restrict__ expK, float* __restrict__ expKV,
                    int M, int N, int K)
{
    __shared__ float As[BK][LDA];
    __shared__ float Ks[BK][LDB];
    __shared__ float Vs[BK][LDB];
    const int tid = threadIdx.x;
    const int tx = tid & 15, ty = tid >> 4;
    const int row0 = blockIdx.y * BM;
    const int col0 = blockIdx.x * BN;
    const int la_row = tid >> 2, la_col = (tid & 3) * 4;
    const int lw_row = tid >> 4, lw_col = (tid & 15) * 4;

    float acck[4][4] = {};
    float accv[4][4] = {};

    const float* Xp  = X  + (size_t)(row0 + la_row) * K + la_col;
    const float* Wkp = Wk + (size_t)lw_row * N + col0 + lw_col;
    const float* Wvp = Wv + (size_t)lw_row * N + col0 + lw_col;

    for (int k0 = 0; k0 < K; k0 += BK) {
        float4 av = *(const float4*)(Xp + k0);
        float4 kv = *(const float4*)(Wkp + (size_t)k0 * N);
        float4 vv = *(const float4*)(Wvp + (size_t)k0 * N);
        As[la_col + 0][la_row] = av.x;
        As[la_col + 1][la_row] = av.y;
        As[la_col + 2][la_row] = av.z;
        As[la_col + 3][la_row] = av.w;
        *(float4*)&Ks[lw_row][lw_col] = kv;
        *(float4*)&Vs[lw_row][lw_col] = vv;
        __syncthreads();
#pragma unroll
        for (int kk = 0; kk < BK; ++kk) {
            float4 a4 = *(const float4*)&As[kk][ty * 4];
            float4 k4 = *(const float4*)&Ks[kk][tx * 4];
            float4 v4 = *(const float4*)&Vs[kk][tx * 4];
            float aa[4] = {a4.x, a4.y, a4.z, a4.w};
            float kkv[4] = {k4.x, k4.y, k4.z, k4.w};
            float vvv[4] = {v4.x, v4.y, v4.z, v4.w};
#pragma unroll
            for (int i = 0; i < 4; ++i)
#pragma unroll
                for (int j = 0; j < 4; ++j) {
                    acck[i][j] = fmaf(aa[i], kkv[j], acck[i][j]);
                    accv[i][j] = fmaf(aa[i], vvv[j], accv[i][j]);
                }
        }
        __syncthreads();
    }

    float bkv[4], bvv4[4];
#pragma unroll
    for (int j = 0; j < 4; ++j) {
        bkv[j]  = bk[col0 + tx * 4 + j];
        bvv4[j] = bvv[col0 + tx * 4 + j];
    }
#pragma unroll
    for (int i = 0; i < 4; ++i) {
        int r = row0 + ty * 4 + i;
        float4 ek, ev;
        float e0 = expf(acck[i][0] + bkv[0]);
        float e1 = expf(acck[i][1] + bkv[1]);
        float e2 = expf(acck[i][2] + bkv[2]);
        float e3 = expf(acck[i][3] + bkv[3]);
        ek.x = e0; ek.y = e1; ek.z = e2; ek.w = e3;
        ev.x = e0 * (accv[i][0] + bvv4[0]);
        ev.y = e1 * (accv[i][1] + bvv4[1]);
        ev.z = e2 * (accv[i][2] + bvv4[2]);
        ev.w = e3 * (accv[i][3] + bvv4[3]);
        *(float4*)&expK[(size_t)r * N + col0 + tx * 4]  = ek;
        *(float4*)&expKV[(size_t)r * N + col0 + tx * 4] = ev;
    }
}

// Core AFT einsum, fused num+den:
//   num[s,h] = sum_t exp(bias[b,s,t]) * expKV[b,t,h]
//   den[s,h] = sum_t exp(bias[b,s,t]) * expK [b,t,h]
//   Yt[s,h]  = sigQ[b,s,h] * num/den
__global__ __launch_bounds__(256)
void aft_kernel(const float* __restrict__ bias, const float* __restrict__ eK,
                const float* __restrict__ eKV, const float* __restrict__ sigQ,
                float* __restrict__ Yt)
{
    __shared__ float As[BK][LDA];
    __shared__ float Bn[BK][LDB];   // expKV tile
    __shared__ float Bd[BK][LDB];   // expK tile
    const int b = blockIdx.z;
    const int tid = threadIdx.x;
    const int tx = tid & 15, ty = tid >> 4;
    const int row0 = blockIdx.y * BM;   // s
    const int col0 = blockIdx.x * BN;   // h
    const int la_row = tid >> 2, la_col = (tid & 3) * 4;
    const int lw_row = tid >> 4, lw_col = (tid & 15) * 4;

    const float* Ab = bias + (size_t)b * NQ * NKV + (size_t)(row0 + la_row) * NKV + la_col;
    const float* Kb = eK   + (size_t)b * NKV * HD + (size_t)lw_row * HD + col0 + lw_col;
    const float* Vb = eKV  + (size_t)b * NKV * HD + (size_t)lw_row * HD + col0 + lw_col;

    float accn[4][4] = {};
    float accd[4][4] = {};

    for (int k0 = 0; k0 < NKV; k0 += BK) {
        float4 av = *(const float4*)(Ab + k0);
        float4 nv = *(const float4*)(Vb + (size_t)k0 * HD);
        float4 dv = *(const float4*)(Kb + (size_t)k0 * HD);
        As[la_col + 0][la_row] = expf(av.x);
        As[la_col + 1][la_row] = expf(av.y);
        As[la_col + 2][la_row] = expf(av.z);
        As[la_col + 3][la_row] = expf(av.w);
        *(float4*)&Bn[lw_row][lw_col] = nv;
        *(float4*)&Bd[lw_row][lw_col] = dv;
        __syncthreads();
#pragma unroll
        for (int kk = 0; kk < BK; ++kk) {
            float4 a4 = *(const float4*)&As[kk][ty * 4];
            float4 n4 = *(const float4*)&Bn[kk][tx * 4];
            float4 d4 = *(const float4*)&Bd[kk][tx * 4];
            float aa[4] = {a4.x, a4.y, a4.z, a4.w};
            float nn[4] = {n4.x, n4.y, n4.z, n4.w};
            float dd[4] = {d4.x, d4.y, d4.z, d4.w};
#pragma unroll
            for (int i = 0; i < 4; ++i)
#pragma unroll
                for (int j = 0; j < 4; ++j) {
                    accn[i][j] = fmaf(aa[i], nn[j], accn[i][j]);
                    accd[i][j] = fmaf(aa[i], dd[j], accd[i][j]);
                }
        }
        __syncthreads();
    }

#pragma unroll
    for (int i = 0; i < 4; ++i) {
        int s = row0 + ty * 4 + i;
        const float4 sq = *(const float4*)&sigQ[((size_t)b * NQ + s) * HD + col0 + tx * 4];
        float4 o;
        o.x = sq.x * accn[i][0] / accd[i][0];
        o.y = sq.y * accn[i][1] / accd[i][1];
        o.z = sq.z * accn[i][2] / accd[i][2];
        o.w = sq.w * accn[i][3] / accd[i][3];
        *(float4*)&Yt[((size_t)b * NQ + s) * HD + col0 + tx * 4] = o;
    }
}

extern "C" void kernel_launch(void* const* d_in, const int* in_sizes, int n_in,
                              void* d_out, int out_size, void* d_ws, size_t ws_size,
                              hipStream_t stream)
{
    const float* x_q  = (const float*)d_in[0];
    const float* x_kv = (const float*)d_in[1];
    const float* bias = (const float*)d_in[2];
    const float* wq_w = (const float*)d_in[3];
    const float* wq_b = (const float*)d_in[4];
    const float* wk_w = (const float*)d_in[5];
    const float* wk_b = (const float*)d_in[6];
    const float* wv_w = (const float*)d_in[7];
    const float* wv_b = (const float*)d_in[8];
    const float* f2_w = (const float*)d_in[9];
    const float* f2_b = (const float*)d_in[10];
    float* out = (float*)d_out;

    // Workspace layout (fp32): sigQ | expK | expKV | Yt  -> 4 * 16.78 MB = 67 MB
    float* ws = (float*)d_ws;
    const size_t nBH = (size_t)BATCH * NQ * HD;   // 4,194,304
    float* sigQ  = ws;
    float* expK  = ws + nBH;
    float* expKV = ws + 2 * nBH;
    float* Yt    = ws + 3 * nBH;

    const int M = BATCH * NQ;   // 16384
    dim3 blk(256);

    // 1) sigQ = sigmoid(x_q @ wq_w + wq_b)          [16384,1024]@[1024,256]
    gemm_bias_kernel<0><<<dim3(HD / BN, M / BM), blk, 0, stream>>>(
        x_q, wq_w, wq_b, sigQ, M, HD, DIN);

    // 2) expK/expKV from x_kv                        [16384,1024]@[1024,256] x2
    proj_kv_kernel<<<dim3(HD / BN, M / BM), blk, 0, stream>>>(
        x_kv, wk_w, wk_b, wv_w, wv_b, expK, expKV, M, HD, DIN);

    // 3) Yt = sigQ * (exp(bias)@expKV)/(exp(bias)@expK)   per batch 2048x2048x(2*256)
    aft_kernel<<<dim3(HD / BN, NQ / BM, BATCH), blk, 0, stream>>>(
        bias, expK, expKV, sigQ, Yt);

    // 4) out = Yt @ f2_w + f2_b                      [16384,256]@[256,256]
    gemm_bias_kernel<1><<<dim3(HD / BN, M / BM), blk, 0, stream>>>(
        Yt, f2_w, f2_b, out, M, HD, HD);
}

// Round 2
// 763.930 us; speedup vs baseline: 1.3500x; 1.3500x over previous
//
#include <hip/hip_runtime.h>
#include <cstddef>
#include <cstdint>

// Problem constants
#define BATCH 8
#define NQ    2048
#define NKV   2048
#define DIN   1024
#define HD    256

// fp32 vector-GEMM tiling (projection kernels)
#define BM 64
#define BN 64
#define BK 16
#define PAD 4
#define LDA (BM + PAD)
#define LDB (BN + PAD)

typedef __attribute__((ext_vector_type(8))) short bf16x8;
typedef __attribute__((ext_vector_type(4))) float f32x4;

__device__ __forceinline__ float sigmoidf_(float x) {
    return 1.0f / (1.0f + expf(-x));
}

// fp32 -> bf16 round-to-nearest-even
__device__ __forceinline__ unsigned short f2bf(float f) {
    union { float f; unsigned int u; } v;
    v.f = f;
    unsigned int u = v.u;
    return (unsigned short)((u + 0x7FFFu + ((u >> 16) & 1u)) >> 16);
}

// ---------------------------------------------------------------------------
// Generic fp32 GEMM: out = epilogue(X[M,K] @ W[K,N] + bv[N])
// MODE 0: sigmoid epilogue (Q projection) ; MODE 1: plain + bias (final proj)
// ---------------------------------------------------------------------------
template <int MODE>
__global__ __launch_bounds__(256)
void gemm_bias_kernel(const float* __restrict__ X, const float* __restrict__ W,
                      const float* __restrict__ bv, float* __restrict__ out,
                      int M, int N, int K)
{
    __shared__ float As[BK][LDA];
    __shared__ float Ws[BK][LDB];
    const int tid = threadIdx.x;
    const int tx = tid & 15, ty = tid >> 4;
    const int row0 = blockIdx.y * BM;
    const int col0 = blockIdx.x * BN;
    const int la_row = tid >> 2, la_col = (tid & 3) * 4;
    const int lw_row = tid >> 4, lw_col = (tid & 15) * 4;

    float acc[4][4] = {};

    const float* Xp = X + (size_t)(row0 + la_row) * K + la_col;
    const float* Wp = W + (size_t)lw_row * N + col0 + lw_col;

    for (int k0 = 0; k0 < K; k0 += BK) {
        float4 av = *(const float4*)(Xp + k0);
        float4 wv = *(const float4*)(Wp + (size_t)k0 * N);
        As[la_col + 0][la_row] = av.x;
        As[la_col + 1][la_row] = av.y;
        As[la_col + 2][la_row] = av.z;
        As[la_col + 3][la_row] = av.w;
        *(float4*)&Ws[lw_row][lw_col] = wv;
        __syncthreads();
#pragma unroll
        for (int kk = 0; kk < BK; ++kk) {
            float4 a4 = *(const float4*)&As[kk][ty * 4];
            float4 w4 = *(const float4*)&Ws[kk][tx * 4];
            float aa[4] = {a4.x, a4.y, a4.z, a4.w};
            float ww[4] = {w4.x, w4.y, w4.z, w4.w};
#pragma unroll
            for (int i = 0; i < 4; ++i)
#pragma unroll
                for (int j = 0; j < 4; ++j)
                    acc[i][j] = fmaf(aa[i], ww[j], acc[i][j]);
        }
        __syncthreads();
    }

    float bb[4];
#pragma unroll
    for (int j = 0; j < 4; ++j) bb[j] = bv[col0 + tx * 4 + j];
#pragma unroll
    for (int i = 0; i < 4; ++i) {
        int r = row0 + ty * 4 + i;
        float4 o;
        if (MODE == 0) {
            o.x = sigmoidf_(acc[i][0] + bb[0]);
            o.y = sigmoidf_(acc[i][1] + bb[1]);
            o.z = sigmoidf_(acc[i][2] + bb[2]);
            o.w = sigmoidf_(acc[i][3] + bb[3]);
        } else {
            o.x = acc[i][0] + bb[0];
            o.y = acc[i][1] + bb[1];
            o.z = acc[i][2] + bb[2];
            o.w = acc[i][3] + bb[3];
        }
        *(float4*)&out[(size_t)r * N + col0 + tx * 4] = o;
    }
}

// ---------------------------------------------------------------------------
// Fused K/V projection. Outputs are bf16 and TRANSPOSED to [B][H][NKV] so the
// aft MFMA kernel can stage B-operands with contiguous-k 16B loads.
//   eKt [b][h][t] = bf16( exp(x@wk + bk) )
//   eKVt[b][h][t] = bf16( exp(x@wk + bk) * (x@wv + bv) )
// ---------------------------------------------------------------------------
__global__ __launch_bounds__(256)
void proj_kv_kernel(const float* __restrict__ X,
                    const float* __restrict__ Wk, const float* __restrict__ bk,
                    const float* __restrict__ Wv, const float* __restrict__ bvv,
                    unsigned short* __restrict__ eKt,
                    unsigned short* __restrict__ eKVt,
                    int M, int N, int K)
{
    __shared__ float As[BK][LDA];
    __shared__ float Ks[BK][LDB];
    __shared__ float Vs[BK][LDB];
    const int tid = threadIdx.x;
    const int tx = tid & 15, ty = tid >> 4;
    const int row0 = blockIdx.y * BM;
    const int col0 = blockIdx.x * BN;
    const int la_row = tid >> 2, la_col = (tid & 3) * 4;
    const int lw_row = tid >> 4, lw_col = (tid & 15) * 4;

    float acck[4][4] = {};
    float accv[4][4] = {};

    const float* Xp  = X  + (size_t)(row0 + la_row) * K + la_col;
    const float* Wkp = Wk + (size_t)lw_row * N + col0 + lw_col;
    const float* Wvp = Wv + (size_t)lw_row * N + col0 + lw_col;

    for (int k0 = 0; k0 < K; k0 += BK) {
        float4 av = *(const float4*)(Xp + k0);
        float4 kv = *(const float4*)(Wkp + (size_t)k0 * N);
        float4 vv = *(const float4*)(Wvp + (size_t)k0 * N);
        As[la_col + 0][la_row] = av.x;
        As[la_col + 1][la_row] = av.y;
        As[la_col + 2][la_row] = av.z;
        As[la_col + 3][la_row] = av.w;
        *(float4*)&Ks[lw_row][lw_col] = kv;
        *(float4*)&Vs[lw_row][lw_col] = vv;
        __syncthreads();
#pragma unroll
        for (int kk = 0; kk < BK; ++kk) {
            float4 a4 = *(const float4*)&As[kk][ty * 4];
            float4 k4 = *(const float4*)&Ks[kk][tx * 4];
            float4 v4 = *(const float4*)&Vs[kk][tx * 4];
            float aa[4] = {a4.x, a4.y, a4.z, a4.w};
            float kkv[4] = {k4.x, k4.y, k4.z, k4.w};
            float vvv[4] = {v4.x, v4.y, v4.z, v4.w};
#pragma unroll
            for (int i = 0; i < 4; ++i)
#pragma unroll
                for (int j = 0; j < 4; ++j) {
                    acck[i][j] = fmaf(aa[i], kkv[j], acck[i][j]);
                    accv[i][j] = fmaf(aa[i], vvv[j], accv[i][j]);
                }
        }
        __syncthreads();
    }

    float bkv[4], bvv4[4];
#pragma unroll
    for (int j = 0; j < 4; ++j) {
        bkv[j]  = bk[col0 + tx * 4 + j];
        bvv4[j] = bvv[col0 + tx * 4 + j];
    }

    // Transposed bf16 store: [b][h][t]; 64 rows of this block all lie in one
    // batch (64 | 2048).
    const int bidx = row0 >> 11;            // row0 / NKV
    const int t0   = (row0 & (NKV - 1)) + ty * 4;
#pragma unroll
    for (int j = 0; j < 4; ++j) {
        const int c = col0 + tx * 4 + j;
        ushort4 pk, pv;
        unsigned short* pK = (unsigned short*)&pk;
        unsigned short* pV = (unsigned short*)&pv;
#pragma unroll
        for (int i = 0; i < 4; ++i) {
            float e  = expf(acck[i][j] + bkv[j]);
            float ev = e * (accv[i][j] + bvv4[j]);
            pK[i] = f2bf(e);
            pV[i] = f2bf(ev);
        }
        size_t base = ((size_t)bidx * HD + c) * NKV + t0;
        *(ushort4*)&eKt[base]  = pk;
        *(ushort4*)&eKVt[base] = pv;
    }
}

// ---------------------------------------------------------------------------
// Core AFT einsum on bf16 MFMA (16x16x32), dual accumulators (num+den share
// the exp(bias) A-fragments so bf16 rounding of A cancels in the ratio).
//   num[s,h] = sum_t exp(bias[b,s,t]) * expKV[b,t,h]
//   den[s,h] = sum_t exp(bias[b,s,t]) * expK [b,t,h]
//   Yt[s,h]  = sigQ[b,s,h] * num/den
// Tile: 128(s) x 64(h), BK=32, 4 waves each owning 32 rows x 64 cols.
// ---------------------------------------------------------------------------
#define ABM 128
#define ABN 64
#define ABK 32
#define LDS_K 40   // bf16 row stride (80 B): breaks pow2 stride, keeps 16B align

__global__ __launch_bounds__(256, 2)
void aft_mfma_kernel(const float* __restrict__ bias,
                     const unsigned short* __restrict__ eKt,    // [B][HD][NKV]
                     const unsigned short* __restrict__ eKVt,   // [B][HD][NKV]
                     const float* __restrict__ sigQ,
                     float* __restrict__ Yt)
{
    __shared__ unsigned short As[ABM][LDS_K];   // exp(bias) tile, [m][k]
    __shared__ unsigned short Bn[ABN][LDS_K];   // expKV^T tile,  [n][k]
    __shared__ unsigned short Bd[ABN][LDS_K];   // expK^T  tile,  [n][k]

    const int b   = blockIdx.z;
    const int s0  = blockIdx.y * ABM;
    const int h0  = blockIdx.x * ABN;
    const int tid = threadIdx.x;
    const int lane = tid & 63;
    const int wave = tid >> 6;       // 0..3
    const int quad = lane >> 4;      // 0..3
    const int l16  = lane & 15;
    const int wrow = wave * 32;      // wave's row quadrant within ABM

    // staging assignments
    const int a_row  = tid >> 1;          // 0..127
    const int a_koff = (tid & 1) * 16;    // 0 / 16
    const int b_h    = tid >> 2;          // 0..63
    const int b_koff = (tid & 3) * 8;     // 0,8,16,24

    const float* biasP = bias + ((size_t)b * NQ + (s0 + a_row)) * NKV + a_koff;
    const unsigned short* eKp  = eKt  + ((size_t)b * HD + (h0 + b_h)) * NKV + b_koff;
    const unsigned short* eKVp = eKVt + ((size_t)b * HD + (h0 + b_h)) * NKV + b_koff;

    f32x4 accn[2][4] = {};
    f32x4 accd[2][4] = {};

    for (int k0 = 0; k0 < NKV; k0 += ABK) {
        // ---- stage A: 16 fp32 bias -> exp -> bf16 -> 2x ds_write_b128
        float4 f0 = *(const float4*)(biasP + k0);
        float4 f1 = *(const float4*)(biasP + k0 + 4);
        float4 f2 = *(const float4*)(biasP + k0 + 8);
        float4 f3 = *(const float4*)(biasP + k0 + 12);
        ushort4 p0, p1, p2, p3;
        p0.x = f2bf(expf(f0.x)); p0.y = f2bf(expf(f0.y));
        p0.z = f2bf(expf(f0.z)); p0.w = f2bf(expf(f0.w));
        p1.x = f2bf(expf(f1.x)); p1.y = f2bf(expf(f1.y));
        p1.z = f2bf(expf(f1.z)); p1.w = f2bf(expf(f1.w));
        p2.x = f2bf(expf(f2.x)); p2.y = f2bf(expf(f2.y));
        p2.z = f2bf(expf(f2.z)); p2.w = f2bf(expf(f2.w));
        p3.x = f2bf(expf(f3.x)); p3.y = f2bf(expf(f3.y));
        p3.z = f2bf(expf(f3.z)); p3.w = f2bf(expf(f3.w));
        *(ushort4*)&As[a_row][a_koff + 0]  = p0;
        *(ushort4*)&As[a_row][a_koff + 4]  = p1;
        *(ushort4*)&As[a_row][a_koff + 8]  = p2;
        *(ushort4*)&As[a_row][a_koff + 12] = p3;

        // ---- stage B: already bf16 + transposed; 16B contiguous loads
        uint4 kn = *(const uint4*)(eKVp + k0);
        uint4 kd = *(const uint4*)(eKp  + k0);
        *(uint4*)&Bn[b_h][b_koff] = kn;
        *(uint4*)&Bd[b_h][b_koff] = kd;
        __syncthreads();

        // ---- fragments
        bf16x8 af[2], bnf[4], bdf[4];
#pragma unroll
        for (int rt = 0; rt < 2; ++rt)
            af[rt] = *(const bf16x8*)&As[wrow + rt * 16 + l16][quad * 8];
#pragma unroll
        for (int ct = 0; ct < 4; ++ct) {
            bnf[ct] = *(const bf16x8*)&Bn[ct * 16 + l16][quad * 8];
            bdf[ct] = *(const bf16x8*)&Bd[ct * 16 + l16][quad * 8];
        }
#pragma unroll
        for (int rt = 0; rt < 2; ++rt)
#pragma unroll
            for (int ct = 0; ct < 4; ++ct) {
                accn[rt][ct] = __builtin_amdgcn_mfma_f32_16x16x32_bf16(
                    af[rt], bnf[ct], accn[rt][ct], 0, 0, 0);
                accd[rt][ct] = __builtin_amdgcn_mfma_f32_16x16x32_bf16(
                    af[rt], bdf[ct], accd[rt][ct], 0, 0, 0);
            }
        __syncthreads();
    }

    // ---- epilogue: C/D layout col=l16, row=quad*4+reg [m89]
#pragma unroll
    for (int rt = 0; rt < 2; ++rt) {
#pragma unroll
        for (int ct = 0; ct < 4; ++ct) {
#pragma unroll
            for (int r = 0; r < 4; ++r) {
                const int s = s0 + wrow + rt * 16 + quad * 4 + r;
                const int h = h0 + ct * 16 + l16;
                const size_t idx = ((size_t)b * NQ + s) * HD + h;
                const float n = accn[rt][ct][r];
                const float d = accd[rt][ct][r];
                Yt[idx] = sigQ[idx] * n / d;
            }
        }
    }
}

extern "C" void kernel_launch(void* const* d_in, const int* in_sizes, int n_in,
                              void* d_out, int out_size, void* d_ws, size_t ws_size,
                              hipStream_t stream)
{
    const float* x_q  = (const float*)d_in[0];
    const float* x_kv = (const float*)d_in[1];
    const float* bias = (const float*)d_in[2];
    const float* wq_w = (const float*)d_in[3];
    const float* wq_b = (const float*)d_in[4];
    const float* wk_w = (const float*)d_in[5];
    const float* wk_b = (const float*)d_in[6];
    const float* wv_w = (const float*)d_in[7];
    const float* wv_b = (const float*)d_in[8];
    const float* f2_w = (const float*)d_in[9];
    const float* f2_b = (const float*)d_in[10];
    float* out = (float*)d_out;

    // Workspace: sigQ fp32 | Yt fp32 | eKt bf16 | eKVt bf16  (~50 MB)
    float* ws = (float*)d_ws;
    const size_t nBH = (size_t)BATCH * NQ * HD;       // 4,194,304
    float* sigQ = ws;
    float* Yt   = ws + nBH;
    unsigned short* eKt  = (unsigned short*)(ws + 2 * nBH);
    unsigned short* eKVt = eKt + nBH;

    const int M = BATCH * NQ;   // 16384
    dim3 blk(256);

    // 1) sigQ = sigmoid(x_q @ wq_w + wq_b)
    gemm_bias_kernel<0><<<dim3(HD / BN, M / BM), blk, 0, stream>>>(
        x_q, wq_w, wq_b, sigQ, M, HD, DIN);

    // 2) eKt/eKVt (bf16, transposed) from x_kv
    proj_kv_kernel<<<dim3(HD / BN, M / BM), blk, 0, stream>>>(
        x_kv, wk_w, wk_b, wv_w, wv_b, eKt, eKVt, M, HD, DIN);

    // 3) Yt = sigQ * (exp(bias)@expKV)/(exp(bias)@expK)  via bf16 MFMA
    aft_mfma_kernel<<<dim3(HD / ABN, NQ / ABM, BATCH), blk, 0, stream>>>(
        bias, eKt, eKVt, sigQ, Yt);

    // 4) out = Yt @ f2_w + f2_b
    gemm_bias_kernel<1><<<dim3(HD / BN, M / BM), blk, 0, stream>>>(
        Yt, f2_w, f2_b, out, M, HD, HD);
}

// Round 3
// 539.981 us; speedup vs baseline: 1.9099x; 1.4147x over previous
//
#include <hip/hip_runtime.h>
#include <cstddef>
#include <cstdint>

// Problem constants
#define BATCH 8
#define NQ    2048
#define NKV   2048
#define DIN   1024
#define HD    256

typedef __attribute__((ext_vector_type(8))) short bf16x8;
typedef __attribute__((ext_vector_type(4))) float f32x4;

__device__ __forceinline__ float sigmoidf_(float x) {
    return 1.0f / (1.0f + expf(-x));
}

// fp32 -> bf16 round-to-nearest-even
__device__ __forceinline__ unsigned short f2bf(float f) {
    union { float f; unsigned int u; } v;
    v.f = f;
    unsigned int u = v.u;
    return (unsigned short)((u + 0x7FFFu + ((u >> 16) & 1u)) >> 16);
}

// ---------------------------------------------------------------------------
// Weight prep: w [DIN][HD] fp32  ->  wT [HD][DIN] bf16   (3 weights via z)
// Tiny kernel (~0.75 MB read x3); coalescing of writes is poor but total
// bytes are trivial.
// ---------------------------------------------------------------------------
__global__ __launch_bounds__(256)
void wtrans_kernel(const float* __restrict__ w0, const float* __restrict__ w1,
                   const float* __restrict__ w2,
                   unsigned short* __restrict__ t0, unsigned short* __restrict__ t1,
                   unsigned short* __restrict__ t2)
{
    const float* w = (blockIdx.z == 0) ? w0 : (blockIdx.z == 1) ? w1 : w2;
    unsigned short* t = (blockIdx.z == 0) ? t0 : (blockIdx.z == 1) ? t1 : t2;
    const int k0 = blockIdx.y * 64;   // DIN/64 = 16
    const int n0 = blockIdx.x * 64;   // HD/64  = 4
    const int tid = threadIdx.x;
    const int kq = tid >> 4;          // 0..15 -> 4-row group in k
    const int nq = tid & 15;          // 0..15 -> 4-col group in n
    float4 r[4];
#pragma unroll
    for (int i = 0; i < 4; ++i)
        r[i] = *(const float4*)&w[(size_t)(k0 + kq * 4 + i) * HD + n0 + nq * 4];
#pragma unroll
    for (int j = 0; j < 4; ++j) {
        ushort4 o;
        o.x = f2bf(((const float*)&r[0])[j]);
        o.y = f2bf(((const float*)&r[1])[j]);
        o.z = f2bf(((const float*)&r[2])[j]);
        o.w = f2bf(((const float*)&r[3])[j]);
        *(ushort4*)&t[(size_t)(n0 + nq * 4 + j) * DIN + k0 + kq * 4] = o;
    }
}

// ---------------------------------------------------------------------------
// Shared MFMA tiling for projection + aft kernels
// Tile 128(m) x 64(n) x 32(k); 4 waves, each owns a 32x64 quadrant.
// ---------------------------------------------------------------------------
#define ABM 128
#define ABN 64
#define ABK 32
#define LDS_K 40   // bf16 row stride (80 B): breaks pow2 stride, 16B aligned

// ---------------------------------------------------------------------------
// Q projection: sigQ = sigmoid(x_q @ wq + b), bf16 MFMA, fp32 out [M][HD]
// ---------------------------------------------------------------------------
__global__ __launch_bounds__(256, 2)
void proj_q_mfma(const float* __restrict__ X,          // [M][DIN]
                 const unsigned short* __restrict__ WT, // [HD][DIN] bf16
                 const float* __restrict__ bv,
                 float* __restrict__ sigQ)
{
    __shared__ unsigned short As[ABM][LDS_K];
    __shared__ unsigned short Bs[ABN][LDS_K];

    const int m0 = blockIdx.y * ABM;
    const int h0 = blockIdx.x * ABN;
    const int tid = threadIdx.x;
    const int lane = tid & 63;
    const int wave = tid >> 6;
    const int quad = lane >> 4;
    const int l16  = lane & 15;
    const int wrow = wave * 32;

    const int a_row  = tid >> 1;
    const int a_koff = (tid & 1) * 16;
    const int b_h    = tid >> 2;
    const int b_koff = (tid & 3) * 8;

    const float* Xp = X + (size_t)(m0 + a_row) * DIN + a_koff;
    const unsigned short* Wp = WT + (size_t)(h0 + b_h) * DIN + b_koff;

    f32x4 acc[2][4] = {};

    for (int k0 = 0; k0 < DIN; k0 += ABK) {
        float4 f0 = *(const float4*)(Xp + k0);
        float4 f1 = *(const float4*)(Xp + k0 + 4);
        float4 f2 = *(const float4*)(Xp + k0 + 8);
        float4 f3 = *(const float4*)(Xp + k0 + 12);
        ushort4 p0, p1, p2, p3;
        p0.x = f2bf(f0.x); p0.y = f2bf(f0.y); p0.z = f2bf(f0.z); p0.w = f2bf(f0.w);
        p1.x = f2bf(f1.x); p1.y = f2bf(f1.y); p1.z = f2bf(f1.z); p1.w = f2bf(f1.w);
        p2.x = f2bf(f2.x); p2.y = f2bf(f2.y); p2.z = f2bf(f2.z); p2.w = f2bf(f2.w);
        p3.x = f2bf(f3.x); p3.y = f2bf(f3.y); p3.z = f2bf(f3.z); p3.w = f2bf(f3.w);
        *(ushort4*)&As[a_row][a_koff + 0]  = p0;
        *(ushort4*)&As[a_row][a_koff + 4]  = p1;
        *(ushort4*)&As[a_row][a_koff + 8]  = p2;
        *(ushort4*)&As[a_row][a_koff + 12] = p3;
        *(uint4*)&Bs[b_h][b_koff] = *(const uint4*)(Wp + k0);
        __syncthreads();

        bf16x8 af[2], bf[4];
#pragma unroll
        for (int rt = 0; rt < 2; ++rt)
            af[rt] = *(const bf16x8*)&As[wrow + rt * 16 + l16][quad * 8];
#pragma unroll
        for (int ct = 0; ct < 4; ++ct)
            bf[ct] = *(const bf16x8*)&Bs[ct * 16 + l16][quad * 8];
#pragma unroll
        for (int rt = 0; rt < 2; ++rt)
#pragma unroll
            for (int ct = 0; ct < 4; ++ct)
                acc[rt][ct] = __builtin_amdgcn_mfma_f32_16x16x32_bf16(
                    af[rt], bf[ct], acc[rt][ct], 0, 0, 0);
        __syncthreads();
    }

#pragma unroll
    for (int rt = 0; rt < 2; ++rt)
#pragma unroll
        for (int ct = 0; ct < 4; ++ct) {
            const int h = h0 + ct * 16 + l16;
            const float bb = bv[h];
#pragma unroll
            for (int r = 0; r < 4; ++r) {
                const int s = m0 + wrow + rt * 16 + quad * 4 + r;
                sigQ[(size_t)s * HD + h] = sigmoidf_(acc[rt][ct][r] + bb);
            }
        }
}

// ---------------------------------------------------------------------------
// K/V projection (dual acc, shared A): outputs bf16, transposed [B][HD][NKV]
//   eKt  = bf16(exp(x@wk + bk))
//   eKVt = bf16(exp(x@wk + bk) * (x@wv + bv))
// ---------------------------------------------------------------------------
__global__ __launch_bounds__(256, 2)
void proj_kv_mfma(const float* __restrict__ X,            // [M][DIN]
                  const unsigned short* __restrict__ WKT, // [HD][DIN]
                  const float* __restrict__ bk,
                  const unsigned short* __restrict__ WVT, // [HD][DIN]
                  const float* __restrict__ bvv,
                  unsigned short* __restrict__ eKt,
                  unsigned short* __restrict__ eKVt)
{
    __shared__ unsigned short As[ABM][LDS_K];
    __shared__ unsigned short Bk[ABN][LDS_K];
    __shared__ unsigned short Bv[ABN][LDS_K];

    const int m0 = blockIdx.y * ABM;
    const int h0 = blockIdx.x * ABN;
    const int tid = threadIdx.x;
    const int lane = tid & 63;
    const int wave = tid >> 6;
    const int quad = lane >> 4;
    const int l16  = lane & 15;
    const int wrow = wave * 32;

    const int a_row  = tid >> 1;
    const int a_koff = (tid & 1) * 16;
    const int b_h    = tid >> 2;
    const int b_koff = (tid & 3) * 8;

    const float* Xp = X + (size_t)(m0 + a_row) * DIN + a_koff;
    const unsigned short* WKp = WKT + (size_t)(h0 + b_h) * DIN + b_koff;
    const unsigned short* WVp = WVT + (size_t)(h0 + b_h) * DIN + b_koff;

    f32x4 acck[2][4] = {};
    f32x4 accv[2][4] = {};

    for (int k0 = 0; k0 < DIN; k0 += ABK) {
        float4 f0 = *(const float4*)(Xp + k0);
        float4 f1 = *(const float4*)(Xp + k0 + 4);
        float4 f2 = *(const float4*)(Xp + k0 + 8);
        float4 f3 = *(const float4*)(Xp + k0 + 12);
        ushort4 p0, p1, p2, p3;
        p0.x = f2bf(f0.x); p0.y = f2bf(f0.y); p0.z = f2bf(f0.z); p0.w = f2bf(f0.w);
        p1.x = f2bf(f1.x); p1.y = f2bf(f1.y); p1.z = f2bf(f1.z); p1.w = f2bf(f1.w);
        p2.x = f2bf(f2.x); p2.y = f2bf(f2.y); p2.z = f2bf(f2.z); p2.w = f2bf(f2.w);
        p3.x = f2bf(f3.x); p3.y = f2bf(f3.y); p3.z = f2bf(f3.z); p3.w = f2bf(f3.w);
        *(ushort4*)&As[a_row][a_koff + 0]  = p0;
        *(ushort4*)&As[a_row][a_koff + 4]  = p1;
        *(ushort4*)&As[a_row][a_koff + 8]  = p2;
        *(ushort4*)&As[a_row][a_koff + 12] = p3;
        *(uint4*)&Bk[b_h][b_koff] = *(const uint4*)(WKp + k0);
        *(uint4*)&Bv[b_h][b_koff] = *(const uint4*)(WVp + k0);
        __syncthreads();

        bf16x8 af[2], bkf[4], bvf[4];
#pragma unroll
        for (int rt = 0; rt < 2; ++rt)
            af[rt] = *(const bf16x8*)&As[wrow + rt * 16 + l16][quad * 8];
#pragma unroll
        for (int ct = 0; ct < 4; ++ct) {
            bkf[ct] = *(const bf16x8*)&Bk[ct * 16 + l16][quad * 8];
            bvf[ct] = *(const bf16x8*)&Bv[ct * 16 + l16][quad * 8];
        }
#pragma unroll
        for (int rt = 0; rt < 2; ++rt)
#pragma unroll
            for (int ct = 0; ct < 4; ++ct) {
                acck[rt][ct] = __builtin_amdgcn_mfma_f32_16x16x32_bf16(
                    af[rt], bkf[ct], acck[rt][ct], 0, 0, 0);
                accv[rt][ct] = __builtin_amdgcn_mfma_f32_16x16x32_bf16(
                    af[rt], bvf[ct], accv[rt][ct], 0, 0, 0);
            }
        __syncthreads();
    }

    // epilogue: exp/mul, transposed bf16 store. Rows r=0..3 are consecutive
    // t-values -> pack ushort4, one 8B store per (rt,ct).
    const int bidx = m0 >> 11;              // m0 / NKV (128 | 2048)
    const int tbase = (m0 & (NKV - 1)) + wrow;
#pragma unroll
    for (int rt = 0; rt < 2; ++rt)
#pragma unroll
        for (int ct = 0; ct < 4; ++ct) {
            const int h = h0 + ct * 16 + l16;
            const float bkb = bk[h];
            const float bvb = bvv[h];
            ushort4 pk, pv;
            unsigned short* pK = (unsigned short*)&pk;
            unsigned short* pV = (unsigned short*)&pv;
#pragma unroll
            for (int r = 0; r < 4; ++r) {
                float e  = expf(acck[rt][ct][r] + bkb);
                float ev = e * (accv[rt][ct][r] + bvb);
                pK[r] = f2bf(e);
                pV[r] = f2bf(ev);
            }
            const int t0 = tbase + rt * 16 + quad * 4;
            size_t base = ((size_t)bidx * HD + h) * NKV + t0;
            *(ushort4*)&eKt[base]  = pk;
            *(ushort4*)&eKVt[base] = pv;
        }
}

// ---------------------------------------------------------------------------
// Core AFT einsum on bf16 MFMA (16x16x32), dual accumulators.
//   num[s,h] = sum_t exp(bias[b,s,t]) * expKV[b,t,h]
//   den[s,h] = sum_t exp(bias[b,s,t]) * expK [b,t,h]
//   Yt[s,h]  = sigQ[b,s,h] * num/den
// ---------------------------------------------------------------------------
__global__ __launch_bounds__(256, 2)
void aft_mfma_kernel(const float* __restrict__ bias,
                     const unsigned short* __restrict__ eKt,    // [B][HD][NKV]
                     const unsigned short* __restrict__ eKVt,   // [B][HD][NKV]
                     const float* __restrict__ sigQ,
                     float* __restrict__ Yt)
{
    __shared__ unsigned short As[ABM][LDS_K];
    __shared__ unsigned short Bn[ABN][LDS_K];
    __shared__ unsigned short Bd[ABN][LDS_K];

    const int b   = blockIdx.z;
    const int s0  = blockIdx.y * ABM;
    const int h0  = blockIdx.x * ABN;
    const int tid = threadIdx.x;
    const int lane = tid & 63;
    const int wave = tid >> 6;
    const int quad = lane >> 4;
    const int l16  = lane & 15;
    const int wrow = wave * 32;

    const int a_row  = tid >> 1;
    const int a_koff = (tid & 1) * 16;
    const int b_h    = tid >> 2;
    const int b_koff = (tid & 3) * 8;

    const float* biasP = bias + ((size_t)b * NQ + (s0 + a_row)) * NKV + a_koff;
    const unsigned short* eKp  = eKt  + ((size_t)b * HD + (h0 + b_h)) * NKV + b_koff;
    const unsigned short* eKVp = eKVt + ((size_t)b * HD + (h0 + b_h)) * NKV + b_koff;

    f32x4 accn[2][4] = {};
    f32x4 accd[2][4] = {};

    for (int k0 = 0; k0 < NKV; k0 += ABK) {
        float4 f0 = *(const float4*)(biasP + k0);
        float4 f1 = *(const float4*)(biasP + k0 + 4);
        float4 f2 = *(const float4*)(biasP + k0 + 8);
        float4 f3 = *(const float4*)(biasP + k0 + 12);
        ushort4 p0, p1, p2, p3;
        p0.x = f2bf(expf(f0.x)); p0.y = f2bf(expf(f0.y));
        p0.z = f2bf(expf(f0.z)); p0.w = f2bf(expf(f0.w));
        p1.x = f2bf(expf(f1.x)); p1.y = f2bf(expf(f1.y));
        p1.z = f2bf(expf(f1.z)); p1.w = f2bf(expf(f1.w));
        p2.x = f2bf(expf(f2.x)); p2.y = f2bf(expf(f2.y));
        p2.z = f2bf(expf(f2.z)); p2.w = f2bf(expf(f2.w));
        p3.x = f2bf(expf(f3.x)); p3.y = f2bf(expf(f3.y));
        p3.z = f2bf(expf(f3.z)); p3.w = f2bf(expf(f3.w));
        *(ushort4*)&As[a_row][a_koff + 0]  = p0;
        *(ushort4*)&As[a_row][a_koff + 4]  = p1;
        *(ushort4*)&As[a_row][a_koff + 8]  = p2;
        *(ushort4*)&As[a_row][a_koff + 12] = p3;

        *(uint4*)&Bn[b_h][b_koff] = *(const uint4*)(eKVp + k0);
        *(uint4*)&Bd[b_h][b_koff] = *(const uint4*)(eKp + k0);
        __syncthreads();

        bf16x8 af[2], bnf[4], bdf[4];
#pragma unroll
        for (int rt = 0; rt < 2; ++rt)
            af[rt] = *(const bf16x8*)&As[wrow + rt * 16 + l16][quad * 8];
#pragma unroll
        for (int ct = 0; ct < 4; ++ct) {
            bnf[ct] = *(const bf16x8*)&Bn[ct * 16 + l16][quad * 8];
            bdf[ct] = *(const bf16x8*)&Bd[ct * 16 + l16][quad * 8];
        }
#pragma unroll
        for (int rt = 0; rt < 2; ++rt)
#pragma unroll
            for (int ct = 0; ct < 4; ++ct) {
                accn[rt][ct] = __builtin_amdgcn_mfma_f32_16x16x32_bf16(
                    af[rt], bnf[ct], accn[rt][ct], 0, 0, 0);
                accd[rt][ct] = __builtin_amdgcn_mfma_f32_16x16x32_bf16(
                    af[rt], bdf[ct], accd[rt][ct], 0, 0, 0);
            }
        __syncthreads();
    }

#pragma unroll
    for (int rt = 0; rt < 2; ++rt)
#pragma unroll
        for (int ct = 0; ct < 4; ++ct)
#pragma unroll
            for (int r = 0; r < 4; ++r) {
                const int s = s0 + wrow + rt * 16 + quad * 4 + r;
                const int h = h0 + ct * 16 + l16;
                const size_t idx = ((size_t)b * NQ + s) * HD + h;
                Yt[idx] = sigQ[idx] * accn[rt][ct][r] / accd[rt][ct][r];
            }
}

// ---------------------------------------------------------------------------
// Final fp32 GEMM: out = Yt @ f2_w + f2_b   [16384,256]@[256,256]
// ---------------------------------------------------------------------------
#define BM 64
#define BN 64
#define BK 16
#define PAD 4
#define LDA (BM + PAD)
#define LDB (BN + PAD)

__global__ __launch_bounds__(256)
void gemm_bias_kernel(const float* __restrict__ X, const float* __restrict__ W,
                      const float* __restrict__ bv, float* __restrict__ out,
                      int M, int N, int K)
{
    __shared__ float As[BK][LDA];
    __shared__ float Ws[BK][LDB];
    const int tid = threadIdx.x;
    const int tx = tid & 15, ty = tid >> 4;
    const int row0 = blockIdx.y * BM;
    const int col0 = blockIdx.x * BN;
    const int la_row = tid >> 2, la_col = (tid & 3) * 4;
    const int lw_row = tid >> 4, lw_col = (tid & 15) * 4;

    float acc[4][4] = {};

    const float* Xp = X + (size_t)(row0 + la_row) * K + la_col;
    const float* Wp = W + (size_t)lw_row * N + col0 + lw_col;

    for (int k0 = 0; k0 < K; k0 += BK) {
        float4 av = *(const float4*)(Xp + k0);
        float4 wv = *(const float4*)(Wp + (size_t)k0 * N);
        As[la_col + 0][la_row] = av.x;
        As[la_col + 1][la_row] = av.y;
        As[la_col + 2][la_row] = av.z;
        As[la_col + 3][la_row] = av.w;
        *(float4*)&Ws[lw_row][lw_col] = wv;
        __syncthreads();
#pragma unroll
        for (int kk = 0; kk < BK; ++kk) {
            float4 a4 = *(const float4*)&As[kk][ty * 4];
            float4 w4 = *(const float4*)&Ws[kk][tx * 4];
            float aa[4] = {a4.x, a4.y, a4.z, a4.w};
            float ww[4] = {w4.x, w4.y, w4.z, w4.w};
#pragma unroll
            for (int i = 0; i < 4; ++i)
#pragma unroll
                for (int j = 0; j < 4; ++j)
                    acc[i][j] = fmaf(aa[i], ww[j], acc[i][j]);
        }
        __syncthreads();
    }

    float bb[4];
#pragma unroll
    for (int j = 0; j < 4; ++j) bb[j] = bv[col0 + tx * 4 + j];
#pragma unroll
    for (int i = 0; i < 4; ++i) {
        int r = row0 + ty * 4 + i;
        float4 o;
        o.x = acc[i][0] + bb[0];
        o.y = acc[i][1] + bb[1];
        o.z = acc[i][2] + bb[2];
        o.w = acc[i][3] + bb[3];
        *(float4*)&out[(size_t)r * N + col0 + tx * 4] = o;
    }
}

extern "C" void kernel_launch(void* const* d_in, const int* in_sizes, int n_in,
                              void* d_out, int out_size, void* d_ws, size_t ws_size,
                              hipStream_t stream)
{
    const float* x_q  = (const float*)d_in[0];
    const float* x_kv = (const float*)d_in[1];
    const float* bias = (const float*)d_in[2];
    const float* wq_w = (const float*)d_in[3];
    const float* wq_b = (const float*)d_in[4];
    const float* wk_w = (const float*)d_in[5];
    const float* wk_b = (const float*)d_in[6];
    const float* wv_w = (const float*)d_in[7];
    const float* wv_b = (const float*)d_in[8];
    const float* f2_w = (const float*)d_in[9];
    const float* f2_b = (const float*)d_in[10];
    float* out = (float*)d_out;

    // Workspace: sigQ fp32 | Yt fp32 | eKt bf16 | eKVt bf16 | wqT|wkT|wvT bf16
    float* ws = (float*)d_ws;
    const size_t nBH = (size_t)BATCH * NQ * HD;       // 4,194,304
    float* sigQ = ws;
    float* Yt   = ws + nBH;
    unsigned short* eKt  = (unsigned short*)(ws + 2 * nBH);
    unsigned short* eKVt = eKt + nBH;
    unsigned short* wqT  = eKVt + nBH;
    unsigned short* wkT  = wqT + (size_t)HD * DIN;
    unsigned short* wvT  = wkT + (size_t)HD * DIN;

    const int M = BATCH * NQ;   // 16384
    dim3 blk(256);

    // 0) transpose+convert weights to bf16 [HD][DIN]
    wtrans_kernel<<<dim3(HD / 64, DIN / 64, 3), blk, 0, stream>>>(
        wq_w, wk_w, wv_w, wqT, wkT, wvT);

    // 1) sigQ = sigmoid(x_q @ wq + b)  (bf16 MFMA, fp32 out)
    proj_q_mfma<<<dim3(HD / ABN, M / ABM), blk, 0, stream>>>(
        x_q, wqT, wq_b, sigQ);

    // 2) eKt/eKVt (bf16, transposed) from x_kv  (bf16 MFMA)
    proj_kv_mfma<<<dim3(HD / ABN, M / ABM), blk, 0, stream>>>(
        x_kv, wkT, wk_b, wvT, wv_b, eKt, eKVt);

    // 3) Yt = sigQ * (exp(bias)@expKV)/(exp(bias)@expK)  via bf16 MFMA
    aft_mfma_kernel<<<dim3(HD / ABN, NQ / ABM, BATCH), blk, 0, stream>>>(
        bias, eKt, eKVt, sigQ, Yt);

    // 4) out = Yt @ f2_w + f2_b  (fp32, precision guard)
    gemm_bias_kernel<<<dim3(HD / BN, M / BM), blk, 0, stream>>>(
        Yt, f2_w, f2_b, out, M, HD, HD);
}

// Round 4
// 427.434 us; speedup vs baseline: 2.4127x; 1.2633x over previous
//
#include <hip/hip_runtime.h>
#include <cstddef>
#include <cstdint>

// Problem constants
#define BATCH 8
#define NQ    2048
#define NKV   2048
#define DIN   1024
#define HD    256

typedef __attribute__((ext_vector_type(8))) short bf16x8;
typedef __attribute__((ext_vector_type(4))) float f32x4;

__device__ __forceinline__ float sigmoidf_(float x) {
    return 1.0f / (1.0f + expf(-x));
}

// fp32 -> bf16 round-to-nearest-even
__device__ __forceinline__ unsigned short f2bf(float f) {
    union { float f; unsigned int u; } v;
    v.f = f;
    unsigned int u = v.u;
    return (unsigned short)((u + 0x7FFFu + ((u >> 16) & 1u)) >> 16);
}

// async global->LDS, 16 B per lane; lds base must be wave-uniform
#define GLL16(gp, lp)                                                        \
    __builtin_amdgcn_global_load_lds(                                        \
        (const __attribute__((address_space(1))) void*)(gp),                 \
        (__attribute__((address_space(3))) void*)(lp), 16, 0, 0)

// ---------------------------------------------------------------------------
// Weight prep: w [DIN][HD] fp32  ->  wT [HD][DIN] bf16   (3 weights via z)
// ---------------------------------------------------------------------------
__global__ __launch_bounds__(256)
void wtrans_kernel(const float* __restrict__ w0, const float* __restrict__ w1,
                   const float* __restrict__ w2,
                   unsigned short* __restrict__ t0, unsigned short* __restrict__ t1,
                   unsigned short* __restrict__ t2)
{
    const float* w = (blockIdx.z == 0) ? w0 : (blockIdx.z == 1) ? w1 : w2;
    unsigned short* t = (blockIdx.z == 0) ? t0 : (blockIdx.z == 1) ? t1 : t2;
    const int k0 = blockIdx.y * 64;
    const int n0 = blockIdx.x * 64;
    const int tid = threadIdx.x;
    const int kq = tid >> 4;
    const int nq = tid & 15;
    float4 r[4];
#pragma unroll
    for (int i = 0; i < 4; ++i)
        r[i] = *(const float4*)&w[(size_t)(k0 + kq * 4 + i) * HD + n0 + nq * 4];
#pragma unroll
    for (int j = 0; j < 4; ++j) {
        ushort4 o;
        o.x = f2bf(((const float*)&r[0])[j]);
        o.y = f2bf(((const float*)&r[1])[j]);
        o.z = f2bf(((const float*)&r[2])[j]);
        o.w = f2bf(((const float*)&r[3])[j]);
        *(ushort4*)&t[(size_t)(n0 + nq * 4 + j) * DIN + k0 + kq * 4] = o;
    }
}

// ---------------------------------------------------------------------------
// Shared tiling: 64(m) x 256(n full) x 32(k). 4 waves; wave w owns the
// 64-wide h-strip [w*64, w*64+64) for all 64 m-rows.
// A: padded LDS (stride 40), staged via regular ds_write (needs transform).
// B: unpadded [256*32], staged via global_load_lds with chunk-XOR swizzle
//    (chunk c of row holds global k-chunk c ^ ((row>>1)&3)) -> frag reads 2-way.
// Ping-pong buffers, ONE __syncthreads per k-iter.
// ---------------------------------------------------------------------------
#define TS 64
#define TH 256
#define TK 32
#define A_LD 40

// ---------------------------------------------------------------------------
// Q projection: sigQ = sigmoid(x_q @ wq + b)   [16384,1024]@[1024,256]
// ---------------------------------------------------------------------------
__global__ __launch_bounds__(256, 1)
void proj_q_mfma(const float* __restrict__ X,
                 const unsigned short* __restrict__ WT,  // [HD][DIN]
                 const float* __restrict__ bv,
                 float* __restrict__ sigQ)
{
    __shared__ unsigned short As[2][TS][A_LD];
    __shared__ unsigned short Bs[2][TH * TK];

    const int m0 = blockIdx.x * TS;
    const int tid = threadIdx.x;
    const int lane = tid & 63, wave = tid >> 6;
    const int quad = lane >> 4, l16 = lane & 15;

    const int a_row = tid >> 2, a_koff = (tid & 3) * 8;
    const float* aP = X + (size_t)(m0 + a_row) * DIN + a_koff;

    const unsigned short* bP[4];
    int ldsOff[4];
#pragma unroll
    for (int j = 0; j < 4; ++j) {
        int idx = j * 256 + tid;
        int row = idx >> 2, c = idx & 3;
        int kc = c ^ ((row >> 1) & 3);
        bP[j] = WT + (size_t)row * DIN + kc * 8;
        ldsOff[j] = (j * 256 + wave * 64) * 16;
    }

    f32x4 acc[4][4] = {};
    float4 a0 = *(const float4*)aP;
    float4 a1 = *(const float4*)(aP + 4);

    for (int k0 = 0; k0 < DIN; k0 += TK) {
        const int p = (k0 >> 5) & 1;
        ushort4 q0, q1;
        q0.x = f2bf(a0.x); q0.y = f2bf(a0.y); q0.z = f2bf(a0.z); q0.w = f2bf(a0.w);
        q1.x = f2bf(a1.x); q1.y = f2bf(a1.y); q1.z = f2bf(a1.z); q1.w = f2bf(a1.w);
        *(ushort4*)&As[p][a_row][a_koff]     = q0;
        *(ushort4*)&As[p][a_row][a_koff + 4] = q1;
        char* bL = (char*)&Bs[p][0];
#pragma unroll
        for (int j = 0; j < 4; ++j)
            GLL16(bP[j] + k0, bL + ldsOff[j]);
        __syncthreads();
        if (k0 + TK < DIN) {
            a0 = *(const float4*)(aP + k0 + TK);
            a1 = *(const float4*)(aP + k0 + TK + 4);
        }
        bf16x8 af[4], bf[4];
#pragma unroll
        for (int rt = 0; rt < 4; ++rt)
            af[rt] = *(const bf16x8*)&As[p][rt * 16 + l16][quad * 8];
#pragma unroll
        for (int ct = 0; ct < 4; ++ct) {
            int row = wave * 64 + ct * 16 + l16;
            int off = row * 64 + ((quad ^ ((row >> 1) & 3)) * 16);
            bf[ct] = *(const bf16x8*)((const char*)&Bs[p][0] + off);
        }
#pragma unroll
        for (int rt = 0; rt < 4; ++rt)
#pragma unroll
            for (int ct = 0; ct < 4; ++ct)
                acc[rt][ct] = __builtin_amdgcn_mfma_f32_16x16x32_bf16(
                    af[rt], bf[ct], acc[rt][ct], 0, 0, 0);
        __syncthreads();
    }

#pragma unroll
    for (int rt = 0; rt < 4; ++rt)
#pragma unroll
        for (int ct = 0; ct < 4; ++ct) {
            const int h = wave * 64 + ct * 16 + l16;
            const float bb = bv[h];
#pragma unroll
            for (int r = 0; r < 4; ++r) {
                const int m = m0 + rt * 16 + quad * 4 + r;
                sigQ[(size_t)m * HD + h] = sigmoidf_(acc[rt][ct][r] + bb);
            }
        }
}

// ---------------------------------------------------------------------------
// K/V projection (dual B, shared A): outputs bf16, transposed [B][HD][NKV]
// ---------------------------------------------------------------------------
__global__ __launch_bounds__(256, 1)
void proj_kv_mfma(const float* __restrict__ X,
                  const unsigned short* __restrict__ WKT,
                  const float* __restrict__ bk,
                  const unsigned short* __restrict__ WVT,
                  const float* __restrict__ bvv,
                  unsigned short* __restrict__ eKt,
                  unsigned short* __restrict__ eKVt)
{
    __shared__ unsigned short As[2][TS][A_LD];
    __shared__ unsigned short Bk[2][TH * TK];
    __shared__ unsigned short Bv[2][TH * TK];

    const int m0 = blockIdx.x * TS;
    const int tid = threadIdx.x;
    const int lane = tid & 63, wave = tid >> 6;
    const int quad = lane >> 4, l16 = lane & 15;

    const int a_row = tid >> 2, a_koff = (tid & 3) * 8;
    const float* aP = X + (size_t)(m0 + a_row) * DIN + a_koff;

    const unsigned short* bkP[4];
    const unsigned short* bvP[4];
    int ldsOff[4];
#pragma unroll
    for (int j = 0; j < 4; ++j) {
        int idx = j * 256 + tid;
        int row = idx >> 2, c = idx & 3;
        int kc = c ^ ((row >> 1) & 3);
        bkP[j] = WKT + (size_t)row * DIN + kc * 8;
        bvP[j] = WVT + (size_t)row * DIN + kc * 8;
        ldsOff[j] = (j * 256 + wave * 64) * 16;
    }

    f32x4 acck[4][4] = {};
    f32x4 accv[4][4] = {};
    float4 a0 = *(const float4*)aP;
    float4 a1 = *(const float4*)(aP + 4);

    for (int k0 = 0; k0 < DIN; k0 += TK) {
        const int p = (k0 >> 5) & 1;
        ushort4 q0, q1;
        q0.x = f2bf(a0.x); q0.y = f2bf(a0.y); q0.z = f2bf(a0.z); q0.w = f2bf(a0.w);
        q1.x = f2bf(a1.x); q1.y = f2bf(a1.y); q1.z = f2bf(a1.z); q1.w = f2bf(a1.w);
        *(ushort4*)&As[p][a_row][a_koff]     = q0;
        *(ushort4*)&As[p][a_row][a_koff + 4] = q1;
        char* bkL = (char*)&Bk[p][0];
        char* bvL = (char*)&Bv[p][0];
#pragma unroll
        for (int j = 0; j < 4; ++j) {
            GLL16(bkP[j] + k0, bkL + ldsOff[j]);
            GLL16(bvP[j] + k0, bvL + ldsOff[j]);
        }
        __syncthreads();
        if (k0 + TK < DIN) {
            a0 = *(const float4*)(aP + k0 + TK);
            a1 = *(const float4*)(aP + k0 + TK + 4);
        }
        bf16x8 af[4], bkf[4], bvf[4];
#pragma unroll
        for (int rt = 0; rt < 4; ++rt)
            af[rt] = *(const bf16x8*)&As[p][rt * 16 + l16][quad * 8];
#pragma unroll
        for (int ct = 0; ct < 4; ++ct) {
            int row = wave * 64 + ct * 16 + l16;
            int off = row * 64 + ((quad ^ ((row >> 1) & 3)) * 16);
            bkf[ct] = *(const bf16x8*)((const char*)&Bk[p][0] + off);
            bvf[ct] = *(const bf16x8*)((const char*)&Bv[p][0] + off);
        }
#pragma unroll
        for (int rt = 0; rt < 4; ++rt)
#pragma unroll
            for (int ct = 0; ct < 4; ++ct) {
                acck[rt][ct] = __builtin_amdgcn_mfma_f32_16x16x32_bf16(
                    af[rt], bkf[ct], acck[rt][ct], 0, 0, 0);
                accv[rt][ct] = __builtin_amdgcn_mfma_f32_16x16x32_bf16(
                    af[rt], bvf[ct], accv[rt][ct], 0, 0, 0);
            }
        __syncthreads();
    }

    const int bidx = m0 >> 11;
    const int tb = m0 & (NKV - 1);
#pragma unroll
    for (int rt = 0; rt < 4; ++rt)
#pragma unroll
        for (int ct = 0; ct < 4; ++ct) {
            const int h = wave * 64 + ct * 16 + l16;
            const float bkb = bk[h];
            const float bvb = bvv[h];
            ushort4 pk, pv;
            unsigned short* pK = (unsigned short*)&pk;
            unsigned short* pV = (unsigned short*)&pv;
#pragma unroll
            for (int r = 0; r < 4; ++r) {
                float e  = __expf(acck[rt][ct][r] + bkb);
                float ev = e * (accv[rt][ct][r] + bvb);
                pK[r] = f2bf(e);
                pV[r] = f2bf(ev);
            }
            const int t0 = tb + rt * 16 + quad * 4;
            size_t base = ((size_t)bidx * HD + h) * NKV + t0;
            *(ushort4*)&eKt[base]  = pk;
            *(ushort4*)&eKVt[base] = pv;
        }
}

// ---------------------------------------------------------------------------
// Core AFT einsum: full-H tile, exp(bias) staged once, dual B via gll.
//   Yt[s,h] = sigQ * (exp(bias)@expKV) / (exp(bias)@expK)
// ---------------------------------------------------------------------------
__global__ __launch_bounds__(256, 1)
void aft_mfma_kernel(const float* __restrict__ bias,
                     const unsigned short* __restrict__ eKt,    // [B][HD][NKV]
                     const unsigned short* __restrict__ eKVt,   // [B][HD][NKV]
                     const float* __restrict__ sigQ,
                     float* __restrict__ Yt)
{
    __shared__ unsigned short As[2][TS][A_LD];
    __shared__ unsigned short Bn[2][TH * TK];
    __shared__ unsigned short Bd[2][TH * TK];

    const int b  = blockIdx.y;
    const int s0 = blockIdx.x * TS;
    const int tid = threadIdx.x;
    const int lane = tid & 63, wave = tid >> 6;
    const int quad = lane >> 4, l16 = lane & 15;

    const int a_row = tid >> 2, a_koff = (tid & 3) * 8;
    const float* aP = bias + ((size_t)b * NQ + (s0 + a_row)) * NKV + a_koff;

    const unsigned short* bnP[4];
    const unsigned short* bdP[4];
    int ldsOff[4];
#pragma unroll
    for (int j = 0; j < 4; ++j) {
        int idx = j * 256 + tid;
        int row = idx >> 2, c = idx & 3;
        int kc = c ^ ((row >> 1) & 3);
        bnP[j] = eKVt + ((size_t)b * HD + row) * NKV + kc * 8;
        bdP[j] = eKt  + ((size_t)b * HD + row) * NKV + kc * 8;
        ldsOff[j] = (j * 256 + wave * 64) * 16;
    }

    f32x4 accn[4][4] = {};
    f32x4 accd[4][4] = {};
    float4 a0 = *(const float4*)aP;
    float4 a1 = *(const float4*)(aP + 4);

    for (int k0 = 0; k0 < NKV; k0 += TK) {
        const int p = (k0 >> 5) & 1;
        ushort4 q0, q1;
        q0.x = f2bf(__expf(a0.x)); q0.y = f2bf(__expf(a0.y));
        q0.z = f2bf(__expf(a0.z)); q0.w = f2bf(__expf(a0.w));
        q1.x = f2bf(__expf(a1.x)); q1.y = f2bf(__expf(a1.y));
        q1.z = f2bf(__expf(a1.z)); q1.w = f2bf(__expf(a1.w));
        *(ushort4*)&As[p][a_row][a_koff]     = q0;
        *(ushort4*)&As[p][a_row][a_koff + 4] = q1;
        char* bnL = (char*)&Bn[p][0];
        char* bdL = (char*)&Bd[p][0];
#pragma unroll
        for (int j = 0; j < 4; ++j) {
            GLL16(bnP[j] + k0, bnL + ldsOff[j]);
            GLL16(bdP[j] + k0, bdL + ldsOff[j]);
        }
        __syncthreads();
        if (k0 + TK < NKV) {
            a0 = *(const float4*)(aP + k0 + TK);
            a1 = *(const float4*)(aP + k0 + TK + 4);
        }
        bf16x8 af[4], bnf[4], bdf[4];
#pragma unroll
        for (int rt = 0; rt < 4; ++rt)
            af[rt] = *(const bf16x8*)&As[p][rt * 16 + l16][quad * 8];
#pragma unroll
        for (int ct = 0; ct < 4; ++ct) {
            int row = wave * 64 + ct * 16 + l16;
            int off = row * 64 + ((quad ^ ((row >> 1) & 3)) * 16);
            bnf[ct] = *(const bf16x8*)((const char*)&Bn[p][0] + off);
            bdf[ct] = *(const bf16x8*)((const char*)&Bd[p][0] + off);
        }
#pragma unroll
        for (int rt = 0; rt < 4; ++rt)
#pragma unroll
            for (int ct = 0; ct < 4; ++ct) {
                accn[rt][ct] = __builtin_amdgcn_mfma_f32_16x16x32_bf16(
                    af[rt], bnf[ct], accn[rt][ct], 0, 0, 0);
                accd[rt][ct] = __builtin_amdgcn_mfma_f32_16x16x32_bf16(
                    af[rt], bdf[ct], accd[rt][ct], 0, 0, 0);
            }
        __syncthreads();
    }

#pragma unroll
    for (int rt = 0; rt < 4; ++rt)
#pragma unroll
        for (int ct = 0; ct < 4; ++ct) {
            const int h = wave * 64 + ct * 16 + l16;
#pragma unroll
            for (int r = 0; r < 4; ++r) {
                const int s = s0 + rt * 16 + quad * 4 + r;
                const size_t idx = ((size_t)b * NQ + s) * HD + h;
                Yt[idx] = sigQ[idx] * accn[rt][ct][r] / accd[rt][ct][r];
            }
        }
}

// ---------------------------------------------------------------------------
// Final fp32 GEMM: out = Yt @ f2_w + f2_b   [16384,256]@[256,256]
// ---------------------------------------------------------------------------
#define BM 64
#define BN 64
#define BK 16
#define PADF 4
#define LDAF (BM + PADF)
#define LDBF (BN + PADF)

__global__ __launch_bounds__(256)
void gemm_bias_kernel(const float* __restrict__ X, const float* __restrict__ W,
                      const float* __restrict__ bv, float* __restrict__ out,
                      int M, int N, int K)
{
    __shared__ float As[BK][LDAF];
    __shared__ float Ws[BK][LDBF];
    const int tid = threadIdx.x;
    const int tx = tid & 15, ty = tid >> 4;
    const int row0 = blockIdx.y * BM;
    const int col0 = blockIdx.x * BN;
    const int la_row = tid >> 2, la_col = (tid & 3) * 4;
    const int lw_row = tid >> 4, lw_col = (tid & 15) * 4;

    float acc[4][4] = {};

    const float* Xp = X + (size_t)(row0 + la_row) * K + la_col;
    const float* Wp = W + (size_t)lw_row * N + col0 + lw_col;

    for (int k0 = 0; k0 < K; k0 += BK) {
        float4 av = *(const float4*)(Xp + k0);
        float4 wv = *(const float4*)(Wp + (size_t)k0 * N);
        As[la_col + 0][la_row] = av.x;
        As[la_col + 1][la_row] = av.y;
        As[la_col + 2][la_row] = av.z;
        As[la_col + 3][la_row] = av.w;
        *(float4*)&Ws[lw_row][lw_col] = wv;
        __syncthreads();
#pragma unroll
        for (int kk = 0; kk < BK; ++kk) {
            float4 a4 = *(const float4*)&As[kk][ty * 4];
            float4 w4 = *(const float4*)&Ws[kk][tx * 4];
            float aa[4] = {a4.x, a4.y, a4.z, a4.w};
            float ww[4] = {w4.x, w4.y, w4.z, w4.w};
#pragma unroll
            for (int i = 0; i < 4; ++i)
#pragma unroll
                for (int j = 0; j < 4; ++j)
                    acc[i][j] = fmaf(aa[i], ww[j], acc[i][j]);
        }
        __syncthreads();
    }

    float bb[4];
#pragma unroll
    for (int j = 0; j < 4; ++j) bb[j] = bv[col0 + tx * 4 + j];
#pragma unroll
    for (int i = 0; i < 4; ++i) {
        int r = row0 + ty * 4 + i;
        float4 o;
        o.x = acc[i][0] + bb[0];
        o.y = acc[i][1] + bb[1];
        o.z = acc[i][2] + bb[2];
        o.w = acc[i][3] + bb[3];
        *(float4*)&out[(size_t)r * N + col0 + tx * 4] = o;
    }
}

extern "C" void kernel_launch(void* const* d_in, const int* in_sizes, int n_in,
                              void* d_out, int out_size, void* d_ws, size_t ws_size,
                              hipStream_t stream)
{
    const float* x_q  = (const float*)d_in[0];
    const float* x_kv = (const float*)d_in[1];
    const float* bias = (const float*)d_in[2];
    const float* wq_w = (const float*)d_in[3];
    const float* wq_b = (const float*)d_in[4];
    const float* wk_w = (const float*)d_in[5];
    const float* wk_b = (const float*)d_in[6];
    const float* wv_w = (const float*)d_in[7];
    const float* wv_b = (const float*)d_in[8];
    const float* f2_w = (const float*)d_in[9];
    const float* f2_b = (const float*)d_in[10];
    float* out = (float*)d_out;

    // Workspace: sigQ fp32 | Yt fp32 | eKt bf16 | eKVt bf16 | wqT|wkT|wvT bf16
    float* ws = (float*)d_ws;
    const size_t nBH = (size_t)BATCH * NQ * HD;       // 4,194,304
    float* sigQ = ws;
    float* Yt   = ws + nBH;
    unsigned short* eKt  = (unsigned short*)(ws + 2 * nBH);
    unsigned short* eKVt = eKt + nBH;
    unsigned short* wqT  = eKVt + nBH;
    unsigned short* wkT  = wqT + (size_t)HD * DIN;
    unsigned short* wvT  = wkT + (size_t)HD * DIN;

    const int M = BATCH * NQ;   // 16384
    dim3 blk(256);

    // 0) transpose+convert weights to bf16 [HD][DIN]
    wtrans_kernel<<<dim3(HD / 64, DIN / 64, 3), blk, 0, stream>>>(
        wq_w, wk_w, wv_w, wqT, wkT, wvT);

    // 1) sigQ = sigmoid(x_q @ wq + b)
    proj_q_mfma<<<dim3(M / TS), blk, 0, stream>>>(x_q, wqT, wq_b, sigQ);

    // 2) eKt/eKVt (bf16, transposed) from x_kv
    proj_kv_mfma<<<dim3(M / TS), blk, 0, stream>>>(
        x_kv, wkT, wk_b, wvT, wv_b, eKt, eKVt);

    // 3) Yt = sigQ * (exp(bias)@expKV)/(exp(bias)@expK)
    aft_mfma_kernel<<<dim3(NQ / TS, BATCH), blk, 0, stream>>>(
        bias, eKt, eKVt, sigQ, Yt);

    // 4) out = Yt @ f2_w + f2_b  (fp32, precision guard)
    gemm_bias_kernel<<<dim3(HD / BN, M / BM), blk, 0, stream>>>(
        Yt, f2_w, f2_b, out, M, HD, HD);
}